// Round 15
// baseline (8223.079 us; speedup 1.0000x reference)
//
#include <hip/hip_runtime.h>

#define BB 128
#define TT 1024
#define II 256
#define HH 512
#define OO 256
#define KK 768

typedef _Float16 half8 __attribute__((ext_vector_type(8)));
typedef _Float16 half4v __attribute__((ext_vector_type(4)));
typedef float f32x4 __attribute__((ext_vector_type(4)));
typedef unsigned u32x4 __attribute__((ext_vector_type(4)));
typedef unsigned long long u64_t;

__device__ __forceinline__ float sigm(float x) { return 1.f / (1.f + __expf(-x)); }
__device__ __forceinline__ float tanhfast(float x) {
  float e = __expf(-2.f * fabsf(x));
  return copysignf((1.f - e) / (1.f + e), x);
}

// ---- one-time: W -> fp16 fragment-linear (R12/R13 layout, unchanged) ----
__global__ void __launch_bounds__(64)
prep_w(const float* __restrict__ Wf, const float* __restrict__ Wi,
       const float* __restrict__ Wc, const float* __restrict__ Wo,
       _Float16* __restrict__ W16)
{
  const int bid = blockIdx.x;          // tile*24 + ks
  const int ks = bid % 24, tile = bid / 24;
  const int lane = threadIdx.x;
  const int r = lane & 15, q = lane >> 4;
  const int lu = r >> 2, g = r & 3;
  const int unit = tile * 4 + lu;
  const float* Wg = (g == 0) ? Wf : (g == 1) ? Wi : (g == 2) ? Wc : Wo;
  const float* src = Wg + (size_t)unit * KK + ks * 32 + q * 8;
  float4 w0 = *(const float4*)src;
  float4 w1 = *(const float4*)(src + 4);
  half8 h;
  h[0] = (_Float16)w0.x; h[1] = (_Float16)w0.y; h[2] = (_Float16)w0.z; h[3] = (_Float16)w0.w;
  h[4] = (_Float16)w1.x; h[5] = (_Float16)w1.y; h[6] = (_Float16)w1.z; h[7] = (_Float16)w1.w;
  *(half8*)(W16 + ((size_t)bid * 64 + lane) * 8) = h;
}

// ---- one-time: x [B][T][I] fp32 -> x16 [T][B][I] fp16 (unchanged) ----
__global__ void __launch_bounds__(256)
prep_x(const float* __restrict__ x, _Float16* __restrict__ x16)
{
  const int t = blockIdx.x;
  for (int i = threadIdx.x; i < BB * II / 4; i += 256) {
    const int b = i >> 6, c4 = (i & 63) * 4;
    float4 v = *(const float4*)(x + ((size_t)b * TT + t) * II + c4);
    half4v h;
    h[0] = (_Float16)v.x; h[1] = (_Float16)v.y; h[2] = (_Float16)v.z; h[3] = (_Float16)v.w;
    *(half4v*)(x16 + ((size_t)t * BB + b) * II + c4) = h;
  }
}

__device__ __forceinline__ unsigned pack2(unsigned a, unsigned b) {
  return (a & 0xffffu) | (b << 16);
}
__device__ __forceinline__ unsigned badtag(u32x4 g, unsigned ex) {
  return ((g.x ^ ex) | (g.y ^ ex) | (g.z ^ ex) | (g.w ^ ex)) & 0xFFFF0000u;
}

// ---- persistent LSTM: XCD-local L2 exchange, PAIR-stored flags + tagged payload ----
// grid=256 cooperative (R13 shape): 8 domains x 32 WGs, domain p = gid & 7 -> XCD p.
// VISIBILITY RECIPE (R13-proven, R14's lesson): every cross-WG word is stored
// TWICE -- plain global_store (local-L2 fast path) + sc1 agent atomic (guaranteed
// path). Plain-store-only hung in R14 (600s): the pair is the proven carrier.
// Consumers use R13's alternating loop: sc0 loads (fast, XCD L2) on even
// iterations, agent atomic loads (guaranteed-terminating) on odd.
// NEW vs R13: wave-flag pre-poll (512 B/WG) replaces the 32 KB payload re-poll;
// payload is then loaded once + tag-verified (backstop loop, normally 1 iter).
// Flags cannot corrupt: tags still gate all data.
__global__ void __launch_bounds__(256, 1)
lstm_persist(const _Float16* __restrict__ x16, const _Float16* __restrict__ W16,
             const float* __restrict__ bfp, const float* __restrict__ bip,
             const float* __restrict__ bcp, const float* __restrict__ bop,
             const float* __restrict__ Wlin, const float* __restrict__ blin,
             float* __restrict__ out,
             unsigned* __restrict__ hbuf,    // [2][BB][HH] tagged u32, memset 0
             unsigned* __restrict__ flags)   // [8][128] wave-flags, memset 0
{
  __shared__ __align__(16) char hsb[2][16 * 1024];  // staged h [buf][16 rows][512] fp16

  const int gid = blockIdx.x;
  const int p = gid & 7;          // domain == XCD (R13-validated)
  const int ugh = gid >> 3;       // hidden group 0..31 (16 units)
  const int tid = threadIdx.x;
  const int wn = tid >> 6, lane = tid & 63;
  const int r = lane & 15, q = lane >> 4;
  const int lu = r >> 2, g4 = r & 3;
  const int rsw = (r & 7) << 4;

  // W fragments (R12 layout; tile = ugh*4 + wn)
  half8 wfrag[24];
  {
    const half8* wp = (const half8*)W16 + (size_t)(ugh * 4 + wn) * 24 * 64 + lane;
#pragma unroll
    for (int ks = 0; ks < 24; ++ks) wfrag[ks] = wp[ks * 64];
  }

  const int unit = ugh * 16 + wn * 4 + lu;
  const float bfv = bfp[unit], biv = bip[unit], bcv = bcp[unit], bov = bop[unit];
  float C = 0.0f;
  const int arow = p * 16 + r;    // A (batch) row this lane feeds

  // staging source geometry (R13-proven): group j covers LDS bytes j*4096 + tid*16,
  // i.e. row = 4j + wn, units 8*(lane ^ ((4j+wn)&7)) .. +8
  int unit0[4];
#pragma unroll
  for (int j = 0; j < 4; ++j) unit0[j] = 8 * (lane ^ ((4 * j + wn) & 7));

  const unsigned* fb0 = flags + p * 128 + lane;    // consumer flag slice (0..63)
  const unsigned* fb1 = fb0 + 64;                  // (64..127)
  unsigned* fa = flags + p * 128 + ugh * 4 + wn;   // producer wave-flag

  // prologue: accN = x-part for t=0
  f32x4 accN = {0.f, 0.f, 0.f, 0.f};
  {
    const _Float16* xr = x16 + (size_t)arow * II + q * 8;
#pragma unroll
    for (int ks = 0; ks < 8; ++ks) {
      half8 a = *(const half8*)(xr + ks * 32);
      accN = __builtin_amdgcn_mfma_f32_16x16x32_f16(a, wfrag[ks], accN, 0, 0, 0);
    }
  }

  // ================= time loop =================
  for (int t = 0; t < TT; ++t) {
    f32x4 acc = accN;             // x-part (computed in shadow last step)
    const int buf = t & 1;

    if (t > 0) {
      // ---- 1) wave-flag pre-poll: 2 dwords/lane; alternate sc0 / agent atomic ----
      for (int it = 0;; ++it) {
        unsigned f0, f1;
        if ((it & 1) == 0) {
          asm volatile(
            "global_load_dword %0, %2, off sc0\n\t"
            "global_load_dword %1, %3, off sc0\n\t"
            "s_waitcnt vmcnt(0)"
            : "=&v"(f0), "=&v"(f1) : "v"(fb0), "v"(fb1) : "memory");
        } else {
          f0 = __hip_atomic_load(fb0, __ATOMIC_RELAXED, __HIP_MEMORY_SCOPE_AGENT);
          f1 = __hip_atomic_load(fb1, __ATOMIC_RELAXED, __HIP_MEMORY_SCOPE_AGENT);
        }
        if (__all(f0 >= (unsigned)t && f1 >= (unsigned)t)) break;
        __builtin_amdgcn_s_sleep(1);
      }

      // ---- 2) payload: R13's alternating backstop loop (normally 1 iteration) ----
      const unsigned ex32 = (unsigned)t << 16;
      const unsigned* b0 = hbuf + ((size_t)(buf * BB + p * 16) + 0 + wn) * HH + unit0[0];
      const unsigned* b1 = hbuf + ((size_t)(buf * BB + p * 16) + 4 + wn) * HH + unit0[1];
      const unsigned* b2 = hbuf + ((size_t)(buf * BB + p * 16) + 8 + wn) * HH + unit0[2];
      const unsigned* b3 = hbuf + ((size_t)(buf * BB + p * 16) + 12 + wn) * HH + unit0[3];
      u32x4 G0, G1, G2, G3, G4, G5, G6, G7;
      for (int it = 0;; ++it) {
        if ((it & 1) == 0) {
          asm volatile(
            "global_load_dwordx4 %0, %8, off sc0\n\t"
            "global_load_dwordx4 %1, %8, off offset:16 sc0\n\t"
            "global_load_dwordx4 %2, %9, off sc0\n\t"
            "global_load_dwordx4 %3, %9, off offset:16 sc0\n\t"
            "global_load_dwordx4 %4, %10, off sc0\n\t"
            "global_load_dwordx4 %5, %10, off offset:16 sc0\n\t"
            "global_load_dwordx4 %6, %11, off sc0\n\t"
            "global_load_dwordx4 %7, %11, off offset:16 sc0\n\t"
            "s_waitcnt vmcnt(0)"
            : "=&v"(G0), "=&v"(G1), "=&v"(G2), "=&v"(G3),
              "=&v"(G4), "=&v"(G5), "=&v"(G6), "=&v"(G7)
            : "v"(b0), "v"(b1), "v"(b2), "v"(b3)
            : "memory");
        } else {
          const u64_t* pp;
          u64_t a0, a1, a2, a3;
#define LD4(bp, A, B)                                                            \
          pp = (const u64_t*)(bp);                                               \
          a0 = __hip_atomic_load(pp,     __ATOMIC_RELAXED, __HIP_MEMORY_SCOPE_AGENT); \
          a1 = __hip_atomic_load(pp + 1, __ATOMIC_RELAXED, __HIP_MEMORY_SCOPE_AGENT); \
          a2 = __hip_atomic_load(pp + 2, __ATOMIC_RELAXED, __HIP_MEMORY_SCOPE_AGENT); \
          a3 = __hip_atomic_load(pp + 3, __ATOMIC_RELAXED, __HIP_MEMORY_SCOPE_AGENT); \
          A = (u32x4){(unsigned)a0, (unsigned)(a0 >> 32), (unsigned)a1, (unsigned)(a1 >> 32)}; \
          B = (u32x4){(unsigned)a2, (unsigned)(a2 >> 32), (unsigned)a3, (unsigned)(a3 >> 32)};
          LD4(b0, G0, G1) LD4(b1, G2, G3) LD4(b2, G4, G5) LD4(b3, G6, G7)
#undef LD4
        }
        unsigned bad = badtag(G0, ex32) | badtag(G1, ex32) | badtag(G2, ex32) |
                       badtag(G3, ex32) | badtag(G4, ex32) | badtag(G5, ex32) |
                       badtag(G6, ex32) | badtag(G7, ex32);
        if (bad == 0) break;
        __builtin_amdgcn_s_sleep(1);
      }
      // strip tags -> packed fp16; contiguous per-wave b128 writes (conflict-free)
      char* dst = hsb[buf] + tid * 16;
      *(u32x4*)(dst)         = (u32x4){pack2(G0.x, G0.y), pack2(G0.z, G0.w),
                                       pack2(G1.x, G1.y), pack2(G1.z, G1.w)};
      *(u32x4*)(dst + 4096)  = (u32x4){pack2(G2.x, G2.y), pack2(G2.z, G2.w),
                                       pack2(G3.x, G3.y), pack2(G3.z, G3.w)};
      *(u32x4*)(dst + 8192)  = (u32x4){pack2(G4.x, G4.y), pack2(G4.z, G4.w),
                                       pack2(G5.x, G5.y), pack2(G5.z, G5.w)};
      *(u32x4*)(dst + 12288) = (u32x4){pack2(G6.x, G6.y), pack2(G6.z, G6.w),
                                       pack2(G7.x, G7.y), pack2(G7.z, G7.w)};
      __syncthreads();

      // h-part MFMAs: two independent accumulator chains
      const char* hrow = hsb[buf] + r * 1024;
      f32x4 acc2 = {0.f, 0.f, 0.f, 0.f};
#pragma unroll
      for (int ks = 0; ks < 16; ks += 2) {
        half8 a0 = *(const half8*)(hrow + (((ks)     * 64 + q * 16) ^ rsw));
        half8 a1 = *(const half8*)(hrow + (((ks + 1) * 64 + q * 16) ^ rsw));
        acc  = __builtin_amdgcn_mfma_f32_16x16x32_f16(a0, wfrag[8 + ks], acc, 0, 0, 0);
        acc2 = __builtin_amdgcn_mfma_f32_16x16x32_f16(a1, wfrag[9 + ks], acc2, 0, 0, 0);
      }
#pragma unroll
      for (int i = 0; i < 4; ++i) acc[i] += acc2[i];
    }

    // in-wave 4x4 quad transpose (R9..R13-proven)
    float t1[4], sx[4], pg[4];
#pragma unroll
    for (int i = 0; i < 4; ++i) sx[i] = __shfl_xor(acc[i], 1);
#pragma unroll
    for (int i = 0; i < 4; ++i) t1[i] = ((i & 1) == (g4 & 1)) ? acc[i] : sx[i ^ 1];
#pragma unroll
    for (int i = 0; i < 4; ++i) sx[i] = __shfl_xor(t1[i], 2);
#pragma unroll
    for (int i = 0; i < 4; ++i) pg[i] = ((i & 2) == (g4 & 2)) ? t1[i] : sx[i ^ 2];

    // gates + state; PAIR store payload (R13-proven) -> drain -> lane0 PAIR-flags
    C = sigm(pg[0] + bfv) * C + sigm(pg[1] + biv) * tanhfast(pg[2] + bcv);
    float hn = sigm(pg[3] + bov) * tanhfast(C);
    unsigned hv;
    { _Float16 a16 = (_Float16)hn; hv = (unsigned)__builtin_bit_cast(unsigned short, a16); }
    {
      unsigned val = ((unsigned)(t + 1) << 16) | hv;
      unsigned* sa = hbuf + ((size_t)(((t + 1) & 1)) * BB + p * 16 + q * 4 + g4) * HH + unit;
      asm volatile("global_store_dword %0, %1, off" :: "v"(sa), "v"(val) : "memory");
      __hip_atomic_store(sa, val, __ATOMIC_RELAXED, __HIP_MEMORY_SCOPE_AGENT);
      asm volatile("s_waitcnt vmcnt(0)" ::: "memory");  // wave's payload pair in flight done
      if (lane == 0) {
        unsigned fval = (unsigned)(t + 1);
        asm volatile("global_store_dword %0, %1, off" :: "v"(fa), "v"(fval) : "memory");
        __hip_atomic_store(fa, fval, __ATOMIC_RELAXED, __HIP_MEMORY_SCOPE_AGENT);
      }
    }

    // shadow: x-part for t+1 (off the critical chain)
    if (t + 1 < TT) {
      accN = (f32x4){0.f, 0.f, 0.f, 0.f};
      const _Float16* xr = x16 + ((size_t)(t + 1) * BB + arow) * II + q * 8;
#pragma unroll
      for (int ks = 0; ks < 8; ++ks) {
        half8 a = *(const half8*)(xr + ks * 32);
        accN = __builtin_amdgcn_mfma_f32_16x16x32_f16(a, wfrag[ks], accN, 0, 0, 0);
      }
    }
  }

  // ===== epilogue: poll h_T (tag TT, buffer 0) via agent atomics (R12/R13-proven) =====
  {
    const int erow = p * 16 + (ugh >> 1);
    const int o0 = (ugh & 1) * 128;
    float* hf = (float*)hsb;
    const unsigned* hb = hbuf + (size_t)erow * HH;  // buffer 0
#pragma unroll
    for (int k = 0; k < 2; ++k) {
      int u = tid + k * 256;
      unsigned v;
      for (;;) {
        v = __hip_atomic_load(hb + u, __ATOMIC_RELAXED, __HIP_MEMORY_SCOPE_AGENT);
        if ((v >> 16) == (unsigned)TT) break;
        __builtin_amdgcn_s_sleep(1);
      }
      hf[u] = (float)__builtin_bit_cast(_Float16, (unsigned short)(v & 0xffffu));
    }
    __syncthreads();
    if (tid < 128) {
      int o = o0 + tid;
      float a2 = blin[o];
      const float4* wr = (const float4*)(Wlin + (size_t)o * HH);
#pragma unroll 4
      for (int j = 0; j < 128; ++j) {
        float4 wv = wr[j];
        a2 += wv.x * hf[4 * j] + wv.y * hf[4 * j + 1] +
              wv.z * hf[4 * j + 2] + wv.w * hf[4 * j + 3];
      }
      out[(size_t)erow * OO + o] = a2;
    }
  }
}

extern "C" void kernel_launch(void* const* d_in, const int* in_sizes, int n_in,
                              void* d_out, int out_size, void* d_ws, size_t ws_size,
                              hipStream_t stream) {
  const float* x    = (const float*)d_in[0];
  const float* Wf   = (const float*)d_in[1];
  const float* bf_  = (const float*)d_in[2];
  const float* Wi   = (const float*)d_in[3];
  const float* bi_  = (const float*)d_in[4];
  const float* Wc   = (const float*)d_in[5];
  const float* bc_  = (const float*)d_in[6];
  const float* Wo   = (const float*)d_in[7];
  const float* bo_  = (const float*)d_in[8];
  const float* Wlin = (const float*)d_in[9];
  const float* blin = (const float*)d_in[10];
  float* out = (float*)d_out;

  // ws: flags [32K,36K) | hbuf(tagged u32) [64K,64K+512K) | W16 [1M,4M) | x16 [4M,68M)
  unsigned*  flags = (unsigned*)((char*)d_ws + 32768);
  unsigned*  hbuf  = (unsigned*)((char*)d_ws + 65536);
  _Float16*  W16   = (_Float16*)((char*)d_ws + 1048576);
  _Float16*  x16   = (_Float16*)((char*)d_ws + 4194304);

  // zero flags + hbuf each launch (tag 0 == h_0; flags 0 < first target)
  hipMemsetAsync((char*)d_ws + 32768, 0, 65536 - 32768 + 2u * BB * HH * 4u, stream);
  prep_w<<<dim3(128 * 24), dim3(64), 0, stream>>>(Wf, Wi, Wc, Wo, W16);
  prep_x<<<dim3(TT), dim3(256), 0, stream>>>(x, x16);

  void* args[] = {(void*)&x16, (void*)&W16, (void*)&bf_, (void*)&bi_, (void*)&bc_,
                  (void*)&bo_, (void*)&Wlin, (void*)&blin, (void*)&out,
                  (void*)&hbuf, (void*)&flags};
  hipLaunchCooperativeKernel((const void*)lstm_persist, dim3(256), dim3(256),
                             args, 0, stream);
}

// Round 16
// 4581.969 us; speedup vs baseline: 1.7947x; 1.7947x over previous
//
#include <hip/hip_runtime.h>

#define BB 128
#define TT 1024
#define II 256
#define HH 512
#define OO 256
#define KK 768

typedef _Float16 half8 __attribute__((ext_vector_type(8)));
typedef _Float16 half4v __attribute__((ext_vector_type(4)));
typedef float f32x4 __attribute__((ext_vector_type(4)));
typedef unsigned u32x4 __attribute__((ext_vector_type(4)));
typedef unsigned long long u64_t;

__device__ __forceinline__ float sigm(float x) { return 1.f / (1.f + __expf(-x)); }
__device__ __forceinline__ float tanhfast(float x) {
  float e = __expf(-2.f * fabsf(x));
  return copysignf((1.f - e) / (1.f + e), x);
}

// ---- one-time: W -> fp16 fragment-linear (R12/R13 layout, unchanged) ----
__global__ void __launch_bounds__(64)
prep_w(const float* __restrict__ Wf, const float* __restrict__ Wi,
       const float* __restrict__ Wc, const float* __restrict__ Wo,
       _Float16* __restrict__ W16)
{
  const int bid = blockIdx.x;          // tile*24 + ks
  const int ks = bid % 24, tile = bid / 24;
  const int lane = threadIdx.x;
  const int r = lane & 15, q = lane >> 4;
  const int lu = r >> 2, g = r & 3;
  const int unit = tile * 4 + lu;
  const float* Wg = (g == 0) ? Wf : (g == 1) ? Wi : (g == 2) ? Wc : Wo;
  const float* src = Wg + (size_t)unit * KK + ks * 32 + q * 8;
  float4 w0 = *(const float4*)src;
  float4 w1 = *(const float4*)(src + 4);
  half8 h;
  h[0] = (_Float16)w0.x; h[1] = (_Float16)w0.y; h[2] = (_Float16)w0.z; h[3] = (_Float16)w0.w;
  h[4] = (_Float16)w1.x; h[5] = (_Float16)w1.y; h[6] = (_Float16)w1.z; h[7] = (_Float16)w1.w;
  *(half8*)(W16 + ((size_t)bid * 64 + lane) * 8) = h;
}

// ---- one-time: x [B][T][I] fp32 -> x16 [T][B][I] fp16 (unchanged) ----
__global__ void __launch_bounds__(256)
prep_x(const float* __restrict__ x, _Float16* __restrict__ x16)
{
  const int t = blockIdx.x;
  for (int i = threadIdx.x; i < BB * II / 4; i += 256) {
    const int b = i >> 6, c4 = (i & 63) * 4;
    float4 v = *(const float4*)(x + ((size_t)b * TT + t) * II + c4);
    half4v h;
    h[0] = (_Float16)v.x; h[1] = (_Float16)v.y; h[2] = (_Float16)v.z; h[3] = (_Float16)v.w;
    *(half4v*)(x16 + ((size_t)t * BB + b) * II + c4) = h;
  }
}

__device__ __forceinline__ unsigned pack2(unsigned a, unsigned b) {
  return (a & 0xffffu) | (b << 16);
}
__device__ __forceinline__ unsigned badtag(u32x4 g, unsigned ex) {
  return ((g.x ^ ex) | (g.y ^ ex) | (g.z ^ ex) | (g.w ^ ex)) & 0xFFFF0000u;
}

// ---- persistent LSTM: R13 base + consumer-side SAMPLE PRE-POLL ----
// grid=256 cooperative: 8 domains x 32 WGs, domain p = gid & 7 -> XCD p.
// Producer side BYTE-IDENTICAL to R13 (pair store: plain + sc1 atomic; no
// waits, no flags -- R15 proved producer-side serialization costs ~3.6us/step).
// Consumer: phase-1 polls 128 SAMPLED payload words (one per producer wave:
// row 0, units 4k; each producer wave's 64 stores are ONE wave64 instruction,
// so its sample tagging ~= the wave's store issued). 512 B/WG vs R13's 32 KB
// slab re-read per poll iteration -> ~64x less poll traffic, less L2
// congestion against the awaited stores. Phase-2 = R13's full load +
// alternating tag-verified backstop (correctness rests on tags alone).
__global__ void __launch_bounds__(256, 1)
lstm_persist(const _Float16* __restrict__ x16, const _Float16* __restrict__ W16,
             const float* __restrict__ bfp, const float* __restrict__ bip,
             const float* __restrict__ bcp, const float* __restrict__ bop,
             const float* __restrict__ Wlin, const float* __restrict__ blin,
             float* __restrict__ out,
             unsigned* __restrict__ hbuf)   // [2][BB][HH] tagged u32, memset 0
{
  __shared__ __align__(16) char hsb[2][16 * 1024];  // staged h [buf][16 rows][512] fp16

  const int gid = blockIdx.x;
  const int p = gid & 7;          // domain == XCD (R13-validated)
  const int ugh = gid >> 3;       // hidden group 0..31 (16 units)
  const int tid = threadIdx.x;
  const int wn = tid >> 6, lane = tid & 63;
  const int r = lane & 15, q = lane >> 4;
  const int lu = r >> 2, g4 = r & 3;
  const int rsw = (r & 7) << 4;

  // W fragments (R12 layout; tile = ugh*4 + wn)
  half8 wfrag[24];
  {
    const half8* wp = (const half8*)W16 + (size_t)(ugh * 4 + wn) * 24 * 64 + lane;
#pragma unroll
    for (int ks = 0; ks < 24; ++ks) wfrag[ks] = wp[ks * 64];
  }

  const int unit = ugh * 16 + wn * 4 + lu;
  const float bfv = bfp[unit], biv = bip[unit], bcv = bcp[unit], bov = bop[unit];
  float C = 0.0f;
  const int arow = p * 16 + r;    // A (batch) row this lane feeds

  // staging source geometry (R13-proven): group j covers LDS bytes j*4096 + tid*16,
  // i.e. row = 4j + wn, units 8*(lane ^ ((4j+wn)&7)) .. +8
  int unit0[4];
#pragma unroll
  for (int j = 0; j < 4; ++j) unit0[j] = 8 * (lane ^ ((4 * j + wn) & 7));

  // prologue: accN = x-part for t=0
  f32x4 accN = {0.f, 0.f, 0.f, 0.f};
  {
    const _Float16* xr = x16 + (size_t)arow * II + q * 8;
#pragma unroll
    for (int ks = 0; ks < 8; ++ks) {
      half8 a = *(const half8*)(xr + ks * 32);
      accN = __builtin_amdgcn_mfma_f32_16x16x32_f16(a, wfrag[ks], accN, 0, 0, 0);
    }
  }

  // ================= time loop =================
  for (int t = 0; t < TT; ++t) {
    f32x4 acc = accN;             // x-part (computed in shadow last step)
    const int buf = t & 1;

    if (t > 0) {
      const unsigned ex32 = (unsigned)t << 16;

      // ---- phase 1: SAMPLE pre-poll (consumer-only; 512 B/WG) ----
      // word 4k of domain-row 0 is written by lane (q=0,g4=0,lu=k&3) of
      // producer wave (ugh=k>>2, wn=(k&3)... unit layout: unit = 4k covers
      // every producer wave exactly twice over k=0..127; cheap proxy.
      {
        const unsigned* sp = hbuf + ((size_t)(buf * BB + p * 16)) * HH;
        const unsigned* s0 = sp + 4 * lane;          // units 0..252
        const unsigned* s1 = sp + 4 * lane + 256;    // units 256..508
        for (int it = 0;; ++it) {
          unsigned w0, w1;
          if ((it & 1) == 0) {
            asm volatile(
              "global_load_dword %0, %2, off sc0\n\t"
              "global_load_dword %1, %3, off sc0\n\t"
              "s_waitcnt vmcnt(0)"
              : "=&v"(w0), "=&v"(w1) : "v"(s0), "v"(s1) : "memory");
          } else {
            w0 = __hip_atomic_load(s0, __ATOMIC_RELAXED, __HIP_MEMORY_SCOPE_AGENT);
            w1 = __hip_atomic_load(s1, __ATOMIC_RELAXED, __HIP_MEMORY_SCOPE_AGENT);
          }
          if (__all((w0 >> 16) >= (unsigned)t && (w1 >> 16) >= (unsigned)t)) break;
          __builtin_amdgcn_s_sleep(1);
        }
      }

      // ---- phase 2: full payload load + R13 alternating backstop ----
      const unsigned* b0 = hbuf + ((size_t)(buf * BB + p * 16) + 0 + wn) * HH + unit0[0];
      const unsigned* b1 = hbuf + ((size_t)(buf * BB + p * 16) + 4 + wn) * HH + unit0[1];
      const unsigned* b2 = hbuf + ((size_t)(buf * BB + p * 16) + 8 + wn) * HH + unit0[2];
      const unsigned* b3 = hbuf + ((size_t)(buf * BB + p * 16) + 12 + wn) * HH + unit0[3];
      u32x4 G0, G1, G2, G3, G4, G5, G6, G7;
      for (int it = 0;; ++it) {
        if ((it & 1) == 0) {
          asm volatile(
            "global_load_dwordx4 %0, %8, off sc0\n\t"
            "global_load_dwordx4 %1, %8, off offset:16 sc0\n\t"
            "global_load_dwordx4 %2, %9, off sc0\n\t"
            "global_load_dwordx4 %3, %9, off offset:16 sc0\n\t"
            "global_load_dwordx4 %4, %10, off sc0\n\t"
            "global_load_dwordx4 %5, %10, off offset:16 sc0\n\t"
            "global_load_dwordx4 %6, %11, off sc0\n\t"
            "global_load_dwordx4 %7, %11, off offset:16 sc0\n\t"
            "s_waitcnt vmcnt(0)"
            : "=&v"(G0), "=&v"(G1), "=&v"(G2), "=&v"(G3),
              "=&v"(G4), "=&v"(G5), "=&v"(G6), "=&v"(G7)
            : "v"(b0), "v"(b1), "v"(b2), "v"(b3)
            : "memory");
        } else {
          const u64_t* pp;
          u64_t a0, a1, a2, a3;
#define LD4(bp, A, B)                                                            \
          pp = (const u64_t*)(bp);                                               \
          a0 = __hip_atomic_load(pp,     __ATOMIC_RELAXED, __HIP_MEMORY_SCOPE_AGENT); \
          a1 = __hip_atomic_load(pp + 1, __ATOMIC_RELAXED, __HIP_MEMORY_SCOPE_AGENT); \
          a2 = __hip_atomic_load(pp + 2, __ATOMIC_RELAXED, __HIP_MEMORY_SCOPE_AGENT); \
          a3 = __hip_atomic_load(pp + 3, __ATOMIC_RELAXED, __HIP_MEMORY_SCOPE_AGENT); \
          A = (u32x4){(unsigned)a0, (unsigned)(a0 >> 32), (unsigned)a1, (unsigned)(a1 >> 32)}; \
          B = (u32x4){(unsigned)a2, (unsigned)(a2 >> 32), (unsigned)a3, (unsigned)(a3 >> 32)};
          LD4(b0, G0, G1) LD4(b1, G2, G3) LD4(b2, G4, G5) LD4(b3, G6, G7)
#undef LD4
        }
        unsigned bad = badtag(G0, ex32) | badtag(G1, ex32) | badtag(G2, ex32) |
                       badtag(G3, ex32) | badtag(G4, ex32) | badtag(G5, ex32) |
                       badtag(G6, ex32) | badtag(G7, ex32);
        if (bad == 0) break;            // normally first try (sample already passed)
        __builtin_amdgcn_s_sleep(1);
      }
      // strip tags -> packed fp16; contiguous per-wave b128 writes (conflict-free)
      char* dst = hsb[buf] + tid * 16;
      *(u32x4*)(dst)         = (u32x4){pack2(G0.x, G0.y), pack2(G0.z, G0.w),
                                       pack2(G1.x, G1.y), pack2(G1.z, G1.w)};
      *(u32x4*)(dst + 4096)  = (u32x4){pack2(G2.x, G2.y), pack2(G2.z, G2.w),
                                       pack2(G3.x, G3.y), pack2(G3.z, G3.w)};
      *(u32x4*)(dst + 8192)  = (u32x4){pack2(G4.x, G4.y), pack2(G4.z, G4.w),
                                       pack2(G5.x, G5.y), pack2(G5.z, G5.w)};
      *(u32x4*)(dst + 12288) = (u32x4){pack2(G6.x, G6.y), pack2(G6.z, G6.w),
                                       pack2(G7.x, G7.y), pack2(G7.z, G7.w)};
      __syncthreads();

      // h-part MFMAs: two independent accumulator chains
      const char* hrow = hsb[buf] + r * 1024;
      f32x4 acc2 = {0.f, 0.f, 0.f, 0.f};
#pragma unroll
      for (int ks = 0; ks < 16; ks += 2) {
        half8 a0 = *(const half8*)(hrow + (((ks)     * 64 + q * 16) ^ rsw));
        half8 a1 = *(const half8*)(hrow + (((ks + 1) * 64 + q * 16) ^ rsw));
        acc  = __builtin_amdgcn_mfma_f32_16x16x32_f16(a0, wfrag[8 + ks], acc, 0, 0, 0);
        acc2 = __builtin_amdgcn_mfma_f32_16x16x32_f16(a1, wfrag[9 + ks], acc2, 0, 0, 0);
      }
#pragma unroll
      for (int i = 0; i < 4; ++i) acc[i] += acc2[i];
    }

    // in-wave 4x4 quad transpose (R9..R13-proven)
    float t1[4], sx[4], pg[4];
#pragma unroll
    for (int i = 0; i < 4; ++i) sx[i] = __shfl_xor(acc[i], 1);
#pragma unroll
    for (int i = 0; i < 4; ++i) t1[i] = ((i & 1) == (g4 & 1)) ? acc[i] : sx[i ^ 1];
#pragma unroll
    for (int i = 0; i < 4; ++i) sx[i] = __shfl_xor(t1[i], 2);
#pragma unroll
    for (int i = 0; i < 4; ++i) pg[i] = ((i & 2) == (g4 & 2)) ? t1[i] : sx[i ^ 2];

    // gates + state; PAIR store (R13-proven, untouched): plain + sc1 atomic
    C = sigm(pg[0] + bfv) * C + sigm(pg[1] + biv) * tanhfast(pg[2] + bcv);
    float hn = sigm(pg[3] + bov) * tanhfast(C);
    unsigned hv;
    { _Float16 a16 = (_Float16)hn; hv = (unsigned)__builtin_bit_cast(unsigned short, a16); }
    {
      unsigned val = ((unsigned)(t + 1) << 16) | hv;
      unsigned* sa = hbuf + ((size_t)(((t + 1) & 1)) * BB + p * 16 + q * 4 + g4) * HH + unit;
      asm volatile("global_store_dword %0, %1, off" :: "v"(sa), "v"(val) : "memory");
      __hip_atomic_store(sa, val, __ATOMIC_RELAXED, __HIP_MEMORY_SCOPE_AGENT);
    }

    // shadow: x-part for t+1 (off the critical chain)
    if (t + 1 < TT) {
      accN = (f32x4){0.f, 0.f, 0.f, 0.f};
      const _Float16* xr = x16 + ((size_t)(t + 1) * BB + arow) * II + q * 8;
#pragma unroll
      for (int ks = 0; ks < 8; ++ks) {
        half8 a = *(const half8*)(xr + ks * 32);
        accN = __builtin_amdgcn_mfma_f32_16x16x32_f16(a, wfrag[ks], accN, 0, 0, 0);
      }
    }
  }

  // ===== epilogue: poll h_T (tag TT, buffer 0) via agent atomics (R12/R13-proven) =====
  {
    const int erow = p * 16 + (ugh >> 1);
    const int o0 = (ugh & 1) * 128;
    float* hf = (float*)hsb;
    const unsigned* hb = hbuf + (size_t)erow * HH;  // buffer 0
#pragma unroll
    for (int k = 0; k < 2; ++k) {
      int u = tid + k * 256;
      unsigned v;
      for (;;) {
        v = __hip_atomic_load(hb + u, __ATOMIC_RELAXED, __HIP_MEMORY_SCOPE_AGENT);
        if ((v >> 16) == (unsigned)TT) break;
        __builtin_amdgcn_s_sleep(1);
      }
      hf[u] = (float)__builtin_bit_cast(_Float16, (unsigned short)(v & 0xffffu));
    }
    __syncthreads();
    if (tid < 128) {
      int o = o0 + tid;
      float a2 = blin[o];
      const float4* wr = (const float4*)(Wlin + (size_t)o * HH);
#pragma unroll 4
      for (int j = 0; j < 128; ++j) {
        float4 wv = wr[j];
        a2 += wv.x * hf[4 * j] + wv.y * hf[4 * j + 1] +
              wv.z * hf[4 * j + 2] + wv.w * hf[4 * j + 3];
      }
      out[(size_t)erow * OO + o] = a2;
    }
  }
}

extern "C" void kernel_launch(void* const* d_in, const int* in_sizes, int n_in,
                              void* d_out, int out_size, void* d_ws, size_t ws_size,
                              hipStream_t stream) {
  const float* x    = (const float*)d_in[0];
  const float* Wf   = (const float*)d_in[1];
  const float* bf_  = (const float*)d_in[2];
  const float* Wi   = (const float*)d_in[3];
  const float* bi_  = (const float*)d_in[4];
  const float* Wc   = (const float*)d_in[5];
  const float* bc_  = (const float*)d_in[6];
  const float* Wo   = (const float*)d_in[7];
  const float* bo_  = (const float*)d_in[8];
  const float* Wlin = (const float*)d_in[9];
  const float* blin = (const float*)d_in[10];
  float* out = (float*)d_out;

  // ws: hbuf(tagged u32) [64K, 64K+512K) | W16 [1M,4M) | x16 [4M,68M)
  unsigned*  hbuf = (unsigned*)((char*)d_ws + 65536);
  _Float16*  W16  = (_Float16*)((char*)d_ws + 1048576);
  _Float16*  x16  = (_Float16*)((char*)d_ws + 4194304);

  hipMemsetAsync((char*)d_ws + 65536, 0, 2u * BB * HH * 4u, stream);
  prep_w<<<dim3(128 * 24), dim3(64), 0, stream>>>(Wf, Wi, Wc, Wo, W16);
  prep_x<<<dim3(TT), dim3(256), 0, stream>>>(x, x16);

  void* args[] = {(void*)&x16, (void*)&W16, (void*)&bf_, (void*)&bi_, (void*)&bc_,
                  (void*)&bo_, (void*)&Wlin, (void*)&blin, (void*)&out, (void*)&hbuf};
  hipLaunchCooperativeKernel((const void*)lstm_persist, dim3(256), dim3(256),
                             args, 0, stream);
}